// Round 11
// baseline (121.574 us; speedup 1.0000x reference)
//
#include <hip/hip_runtime.h>
#include <hip/hip_bf16.h>

typedef __attribute__((ext_vector_type(4))) float  floatx4;
typedef __attribute__((ext_vector_type(2))) float  floatx2;
typedef __attribute__((ext_vector_type(8))) __bf16 bf16x8;

#define FP8_MAX 448.0f

// HW OCP e4m3fn round-trip (RNE), matches ml_dtypes float8_e4m3fn for |v|<=448
__device__ __forceinline__ floatx2 fp8_qdq2(float a, float b) {
    int p = __builtin_amdgcn_cvt_pk_fp8_f32(a, b, 0, false);
    return __builtin_amdgcn_cvt_pk_f32_fp8(p, false);
}

__device__ __forceinline__ unsigned int f2bf(float f) {
    union { __hip_bfloat16 h; unsigned short u; } cv;
    cv.h = __float2bfloat16(f);
    return (unsigned int)cv.u;
}

__device__ __forceinline__ void async_copy16(void* lds, const void* g) {
    __builtin_amdgcn_global_load_lds(
        (const __attribute__((address_space(1))) unsigned int*)g,
        (__attribute__((address_space(3))) unsigned int*)lds, 16, 0, 0);
}

// ---------------------------------------------------------------------------
// Kernel 1: dequantize W [D=512][F=512] (quant blocks of 128 along F),
//           write transposed bf16 Wt [F=512][D=512].
__global__ void wdq_kernel(const float* __restrict__ W,
                           __hip_bfloat16* __restrict__ Wt) {
    const int D = 512, F = 512;
    int d = blockIdx.x;
    int t = threadIdx.x;
    float4 v = *reinterpret_cast<const float4*>(W + (size_t)d * F + t * 4);
    float am = fmaxf(fmaxf(fabsf(v.x), fabsf(v.y)), fmaxf(fabsf(v.z), fabsf(v.w)));
#pragma unroll
    for (int s = 16; s >= 1; s >>= 1) am = fmaxf(am, __shfl_xor(am, s));
    float scale = fmaxf(am, 1e-4f) / FP8_MAX;
    floatx2 d01 = fp8_qdq2(v.x / scale, v.y / scale);
    floatx2 d23 = fp8_qdq2(v.z / scale, v.w / scale);
    int f0 = t * 4;
    Wt[(size_t)(f0 + 0) * D + d] = __float2bfloat16(d01[0] * scale);
    Wt[(size_t)(f0 + 1) * D + d] = __float2bfloat16(d01[1] * scale);
    Wt[(size_t)(f0 + 2) * D + d] = __float2bfloat16(d23[0] * scale);
    Wt[(size_t)(f0 + 3) * D + d] = __float2bfloat16(d23[1] * scale);
}

// ---------------------------------------------------------------------------
// Kernel 2: streaming X quant-dequant f32 -> bf16 (quant blocks 128 along K).
// 1 wave = 1 row (64 lanes x 8 f32); quant block = 16-lane group, shuffle
// xor {1,2,4,8}. float4x2 in, uint4 (8 bf16) out — all 16B-coalesced.
__global__ void xqdq_kernel(const float* __restrict__ X,
                            __hip_bfloat16* __restrict__ Xdq) {
    int tid = threadIdx.x;
    size_t row = (size_t)blockIdx.x * 4 + (tid >> 6);
    int lane = tid & 63;
    const float* src = X + row * 512 + lane * 8;
    float4 v0 = *reinterpret_cast<const float4*>(src);
    float4 v1 = *reinterpret_cast<const float4*>(src + 4);
    float am = fmaxf(fmaxf(fmaxf(fabsf(v0.x), fabsf(v0.y)),
                           fmaxf(fabsf(v0.z), fabsf(v0.w))),
                     fmaxf(fmaxf(fabsf(v1.x), fabsf(v1.y)),
                           fmaxf(fabsf(v1.z), fabsf(v1.w))));
    am = fmaxf(am, __shfl_xor(am, 1));
    am = fmaxf(am, __shfl_xor(am, 2));
    am = fmaxf(am, __shfl_xor(am, 4));
    am = fmaxf(am, __shfl_xor(am, 8));
    am = fmaxf(am, 1e-4f);
    float scale = am / FP8_MAX;           // exact reference scale (IEEE div)
    float inv   = FP8_MAX / am;
    floatx2 a0 = fp8_qdq2(v0.x * inv, v0.y * inv);
    floatx2 a1 = fp8_qdq2(v0.z * inv, v0.w * inv);
    floatx2 a2 = fp8_qdq2(v1.x * inv, v1.y * inv);
    floatx2 a3 = fp8_qdq2(v1.z * inv, v1.w * inv);
    uint4 o;
    o.x = f2bf(a0[0] * scale) | (f2bf(a0[1] * scale) << 16);
    o.y = f2bf(a1[0] * scale) | (f2bf(a1[1] * scale) << 16);
    o.z = f2bf(a2[0] * scale) | (f2bf(a2[1] * scale) << 16);
    o.w = f2bf(a3[0] * scale) | (f2bf(a3[1] * scale) << 16);
    *reinterpret_cast<uint4*>(Xdq + row * 512 + lane * 8) = o;
}

// ---------------------------------------------------------------------------
// Kernel 3: bf16 GEMM, BM=128/BN=128/BK=64, 256 thr = 4 waves (2x2, wave
// tile 64x64, acc 4x4 = 32 MFMA/wave/iter).
// A: LDS TRIPLE-buffered global_load_lds (48 KB -> 3 blocks/CU), issued
//    2 iters ahead; XOR slot swizzle both-sides (0 conflicts, rounds 3-10).
// B: W is 512 KB total -> permanently L2-resident on every XCD. Loaded
//    per-lane straight to registers (bf16x8, 1 KB/wave/instr, 16 rows x
//    64 B), 1 iter ahead, alternating reg sets bA/bB (static indexing).
//    No B LDS, no ds_writes -> barriers wait on nothing but the counted A.
// Boundary: vmcnt(12) = exactly the 12 VMEM ops issued this iter (4 A-DMA
//    + 8 B-loads); guarantees A(t+1) resident under any intra-iter reorder
//    while the 2-ahead A prefetch keeps floating. t==6 issues no A -> (8).
__global__ __launch_bounds__(256, 3) void gemm9(
        const __hip_bfloat16* __restrict__ Xdq,  // [M][512] bf16
        const __hip_bfloat16* __restrict__ Wt,   // [512 f][512 k] bf16
        const float* __restrict__ bias,          // [512]
        float* __restrict__ C, int M) {
    const int K = 512, N = 512;
    __shared__ char Abuf[3][16384];   // [128 r][8 slot16B] bf16, slot ^= r&7

    // XCD-chunked bijective swizzle (grid 2048 % 8 == 0): the 4 tn tiles of
    // each tm adjacent on one XCD -> A-panel L2 reuse.
    int bx   = blockIdx.x;
    int tile = (bx & 7) * (gridDim.x >> 3) + (bx >> 3);
    int tn   = tile & 3;             // N-panel of 128
    int tm   = tile >> 2;            // M-tile of 128 rows

    int tid = threadIdx.x, wid = tid >> 6, lane = tid & 63;
    int wm = wid >> 1, wn = wid & 1; // wave grid 2(M) x 2(N), tile 64x64
    int lr = lane & 15, lg = lane >> 4;

    const char* Abase = (const char*)(Xdq + (size_t)tm * 128 * K);
    const char* Bbase = (const char*)(Wt + (size_t)tn * 128 * K);
    float* Cb = C + (size_t)tm * 128 * N + tn * 128;

    floatx4 acc[4][4] = {};
    bf16x8 bA[8], bB[8];   // b frag sets: [ks*4+ni], alternating iters

    auto stageA = [&](int buf, int t) {
        int kb = t * 128;
#pragma unroll
        for (int i = 0; i < 4; ++i) {
            int c = wid * 4 + i;
            int r = c * 8 + (lane >> 3);
            int s = lane & 7;
            async_copy16(Abuf[buf] + c * 1024,
                         Abase + (size_t)r * 1024 + kb + ((s ^ (r & 7)) << 4));
        }
    };
    auto loadB = [&](bf16x8* b, int t) {
#pragma unroll
        for (int ks = 0; ks < 2; ++ks)
#pragma unroll
            for (int ni = 0; ni < 4; ++ni) {
                int f = wn * 64 + ni * 16 + lr;       // row of Wt panel
                int q = ks * 4 + lg;                  // 16B k-slot in [0,8)
                b[ks * 4 + ni] = *reinterpret_cast<const bf16x8*>(
                    Bbase + (size_t)f * 1024 + t * 128 + q * 16);
            }
    };
    auto mfmaStep = [&](const char* Ab, const bf16x8* b) {
#pragma unroll
        for (int ks = 0; ks < 2; ++ks) {
            int q = (ks << 2) | lg;
            bf16x8 a[4];
#pragma unroll
            for (int mi = 0; mi < 4; ++mi) {
                int r = wm * 64 + mi * 16 + lr;
                a[mi] = *reinterpret_cast<const bf16x8*>(
                    Ab + r * 128 + ((q ^ (r & 7)) << 4));
            }
#pragma unroll
            for (int mi = 0; mi < 4; ++mi)
#pragma unroll
                for (int ni = 0; ni < 4; ++ni)
                    acc[mi][ni] = __builtin_amdgcn_mfma_f32_16x16x32_bf16(
                        a[mi], b[ks * 4 + ni], acc[mi][ni], 0, 0, 0);
        }
    };

    // ---- prologue: bias -> A0 -> A1 -> B0, order pinned -------------------
    float bv[4];
#pragma unroll
    for (int ni = 0; ni < 4; ++ni)
        bv[ni] = bias[tn * 128 + wn * 64 + ni * 16 + lr];
    __builtin_amdgcn_sched_barrier(0);
    stageA(0, 0);
    stageA(1, 1);
    __builtin_amdgcn_sched_barrier(0);
    loadB(bA, 0);
    __builtin_amdgcn_sched_barrier(0);
    asm volatile("s_waitcnt vmcnt(12)" ::: "memory");  // bias+A0 done; A1+B0 float
    __builtin_amdgcn_s_barrier();
    __builtin_amdgcn_sched_barrier(0);

    // ---- main: 8 iters of BK=64, fully unrolled, one barrier each ---------
#pragma unroll
    for (int t = 0; t < 8; ++t) {
        if (t < 6) stageA((t + 2) % 3, t + 2);
        if (t < 7) loadB((t & 1) ? bA : bB, t + 1);
        __builtin_amdgcn_s_setprio(1);
        mfmaStep(Abuf[t % 3], (t & 1) ? bB : bA);
        __builtin_amdgcn_s_setprio(0);
        if (t < 7) {
            if (t < 6) asm volatile("s_waitcnt vmcnt(12)" ::: "memory");
            else       asm volatile("s_waitcnt vmcnt(8)"  ::: "memory");
            __builtin_amdgcn_s_barrier();
            __builtin_amdgcn_sched_barrier(0);
        }
    }

    // ---- epilogue: C/D layout col=lane&15, row=(lane>>4)*4+e --------------
#pragma unroll
    for (int ni = 0; ni < 4; ++ni) {
        int col = wn * 64 + ni * 16 + lr;
#pragma unroll
        for (int mi = 0; mi < 4; ++mi) {
            int r0 = wm * 64 + mi * 16 + lg * 4;
#pragma unroll
            for (int e = 0; e < 4; ++e)
                Cb[(size_t)(r0 + e) * N + col] = acc[mi][ni][e] + bv[ni];
        }
    }
}

// ---------------------------------------------------------------------------
extern "C" void kernel_launch(void* const* d_in, const int* in_sizes, int n_in,
                              void* d_out, int out_size, void* d_ws, size_t ws_size,
                              hipStream_t stream) {
    const float* X    = (const float*)d_in[0];
    const float* W    = (const float*)d_in[1];
    const float* bias = (const float*)d_in[2];
    const int K = 512;
    const int M = in_sizes[0] / K;   // 65536

    __hip_bfloat16* Wt  = (__hip_bfloat16*)d_ws;      // 512 KB
    __hip_bfloat16* Xdq = Wt + 512 * 512;             // 64 MB

    wdq_kernel<<<dim3(512), dim3(128), 0, stream>>>(W, Wt);
    xqdq_kernel<<<dim3(M / 4), dim3(256), 0, stream>>>(X, Xdq);
    gemm9<<<dim3((M / 128) * (512 / 128)), dim3(256), 0, stream>>>(
        Xdq, Wt, bias, (float*)d_out, M);
}

// Round 12
// 89.109 us; speedup vs baseline: 1.3643x; 1.3643x over previous
//
#include <hip/hip_runtime.h>
#include <hip/hip_bf16.h>

typedef __attribute__((ext_vector_type(4))) float  floatx4;
typedef __attribute__((ext_vector_type(2))) float  floatx2;
typedef __attribute__((ext_vector_type(8))) __bf16 bf16x8;

#define FP8_MAX 448.0f

// HW OCP e4m3fn round-trip (RNE), matches ml_dtypes float8_e4m3fn for |v|<=448
__device__ __forceinline__ floatx2 fp8_qdq2(float a, float b) {
    int p = __builtin_amdgcn_cvt_pk_fp8_f32(a, b, 0, false);
    return __builtin_amdgcn_cvt_pk_f32_fp8(p, false);
}

__device__ __forceinline__ unsigned int f2bf(float f) {
    union { __hip_bfloat16 h; unsigned short u; } cv;
    cv.h = __float2bfloat16(f);
    return (unsigned int)cv.u;
}

__device__ __forceinline__ void async_copy16(void* lds, const void* g) {
    __builtin_amdgcn_global_load_lds(
        (const __attribute__((address_space(1))) unsigned int*)g,
        (__attribute__((address_space(3))) unsigned int*)lds, 16, 0, 0);
}

// ---------------------------------------------------------------------------
// Kernel 1: dequantize W [D=512][F=512] (quant blocks of 128 along F),
//           write transposed bf16 Wt [F=512][D=512].
__global__ void wdq_kernel(const float* __restrict__ W,
                           __hip_bfloat16* __restrict__ Wt) {
    const int D = 512, F = 512;
    int d = blockIdx.x;
    int t = threadIdx.x;
    float4 v = *reinterpret_cast<const float4*>(W + (size_t)d * F + t * 4);
    float am = fmaxf(fmaxf(fabsf(v.x), fabsf(v.y)), fmaxf(fabsf(v.z), fabsf(v.w)));
#pragma unroll
    for (int s = 16; s >= 1; s >>= 1) am = fmaxf(am, __shfl_xor(am, s));
    float scale = fmaxf(am, 1e-4f) / FP8_MAX;
    floatx2 d01 = fp8_qdq2(v.x / scale, v.y / scale);
    floatx2 d23 = fp8_qdq2(v.z / scale, v.w / scale);
    int f0 = t * 4;
    Wt[(size_t)(f0 + 0) * D + d] = __float2bfloat16(d01[0] * scale);
    Wt[(size_t)(f0 + 1) * D + d] = __float2bfloat16(d01[1] * scale);
    Wt[(size_t)(f0 + 2) * D + d] = __float2bfloat16(d23[0] * scale);
    Wt[(size_t)(f0 + 3) * D + d] = __float2bfloat16(d23[1] * scale);
}

// ---------------------------------------------------------------------------
// Kernel 2 (fused, round-4 geometry + fully counted boundaries):
// BM=64, BN=256, BK=64; 256 thr = 4 waves (1x4), wave tile 64x64, acc 4x4
// = 32 MFMA/wave/step, 8 steps, ONE {vmcnt(N); lgkmcnt(0); s_barrier} each.
// LDS: As[2][64r][64k] 16 KB + Bs[2][256f][64k] 64 KB = 80 KB -> 2 blk/CU.
// X quant: reg path, two NAMED v-sets (vA/vB), loads issued at even iters
// AFTER that iter's B-DMAs. FIFO (per wave, derived for all 8 iters):
//   even-t boundary: [X_old.8][B.8][X_new.8] -> vmcnt(8) floats X_new
//   odd-t boundary:  [X.8][B.8]              -> vmcnt(0); the X drained here
//     was issued >=1.5 iters ago (~HBM latency) -> nearly free.
// Every quantX consumes X already retired at a prior boundary -> no exposed
// HBM latency at the consumption point. No full drain ever stalls fresh X.
// XOR slot swizzle both-sides (slot ^= row&7): 0 conflicts (rounds 3-11).
__global__ __launch_bounds__(256, 2) void fused_gemm(
        const float* __restrict__ X,             // [M][512] f32
        const __hip_bfloat16* __restrict__ Wt,   // [512 f][512 k] bf16
        const float* __restrict__ bias,          // [512]
        float* __restrict__ C, int M) {
    const int K = 512, N = 512;
    __shared__ char As[2][8192];    // [64 r][8 slot16B], swizzled
    __shared__ char Bs[2][32768];   // [256 f][8 slot16B], swizzled

    // XCD-chunked bijective swizzle (grid 2048 % 8 == 0): tn pair of each tm
    // adjacent on one XCD -> X panel fetched from HBM once.
    int bx   = blockIdx.x;
    int tile = (bx & 7) * (gridDim.x >> 3) + (bx >> 3);
    int tN   = tile & 1;             // N-panel of 256
    int tM   = tile >> 1;            // M-tile of 64 rows

    int tid = threadIdx.x, wid = tid >> 6, lane = tid & 63;
    int wn = wid;                    // wave grid 1(M) x 4(N)
    int lr = lane & 15, lg = lane >> 4;
    int ar = tid >> 2, aq = tid & 3; // A-quant: 4 thr/row, 32 f32 each

    const float* Xb = X + (size_t)(tM * 64) * K;
    const char* Wb  = (const char*)(Wt + (size_t)tN * 256 * K);
    float* Cb = C + (size_t)(tM * 64) * N + tN * 256;

    float4 vA[8], vB[8];   // two X stashes (32 f32 each)
    uint4  q4[4];          // quantized bf16 (32 elems = 4 slots)
    floatx4 acc[4][4] = {};

    auto loadX = [&](float4 (&v)[8], int qb) {
        const float* src = Xb + (size_t)ar * K + qb * 128 + aq * 32;
#pragma unroll
        for (int j = 0; j < 8; ++j)
            v[j] = *reinterpret_cast<const float4*>(src + j * 4);
    };
    auto quantX = [&](const float4 (&v)[8]) {
        float am = 0.f;
#pragma unroll
        for (int j = 0; j < 8; ++j)
            am = fmaxf(am, fmaxf(fmaxf(fabsf(v[j].x), fabsf(v[j].y)),
                                 fmaxf(fabsf(v[j].z), fabsf(v[j].w))));
        am = fmaxf(am, __shfl_xor(am, 1));
        am = fmaxf(am, __shfl_xor(am, 2));
        am = fmaxf(am, 1e-4f);
        float scale = am / FP8_MAX;     // exact reference scale (IEEE div)
        float inv   = FP8_MAX / am;
#pragma unroll
        for (int n = 0; n < 4; ++n) {
            floatx2 a0 = fp8_qdq2(v[2*n].x*inv,   v[2*n].y*inv);
            floatx2 a1 = fp8_qdq2(v[2*n].z*inv,   v[2*n].w*inv);
            floatx2 a2 = fp8_qdq2(v[2*n+1].x*inv, v[2*n+1].y*inv);
            floatx2 a3 = fp8_qdq2(v[2*n+1].z*inv, v[2*n+1].w*inv);
            q4[n].x = f2bf(a0[0]*scale) | (f2bf(a0[1]*scale) << 16);
            q4[n].y = f2bf(a1[0]*scale) | (f2bf(a1[1]*scale) << 16);
            q4[n].z = f2bf(a2[0]*scale) | (f2bf(a2[1]*scale) << 16);
            q4[n].w = f2bf(a3[0]*scale) | (f2bf(a3[1]*scale) << 16);
        }
    };
    auto writeA = [&](int buf, int hb) {   // k-half hb of q4 -> As[buf]
        if ((aq >> 1) == hb) {
#pragma unroll
            for (int n = 0; n < 4; ++n) {
                int slot = (aq & 1) * 4 + n;
                *reinterpret_cast<uint4*>(
                    As[buf] + ar * 128 + ((slot ^ (ar & 7)) << 4)) = q4[n];
            }
        }
    };
    auto stageB = [&](int buf, int step) {   // 32 x 1KB chunks, 8/wave
        const char* base = Wb + step * 128;
#pragma unroll
        for (int cc = 0; cc < 8; ++cc) {
            int c  = wid * 8 + cc;
            int rr = c * 8 + (lane >> 3);
            int d  = lane & 7;
            async_copy16(Bs[buf] + c * 1024,
                         base + (size_t)rr * (K * 2) + ((d ^ (rr & 7)) << 4));
        }
    };
    auto mfmaStep = [&](int buf) {
        __builtin_amdgcn_s_setprio(1);
#pragma unroll
        for (int ks = 0; ks < 2; ++ks) {
            int q = (ks << 2) | lg;
            bf16x8 a[4], b[4];
#pragma unroll
            for (int mi = 0; mi < 4; ++mi) {
                int r = mi * 16 + lr;
                a[mi] = *reinterpret_cast<const bf16x8*>(
                    As[buf] + r * 128 + ((q ^ (r & 7)) << 4));
            }
#pragma unroll
            for (int ni = 0; ni < 4; ++ni) {
                int f = wn * 64 + ni * 16 + lr;
                b[ni] = *reinterpret_cast<const bf16x8*>(
                    Bs[buf] + f * 128 + ((q ^ (f & 7)) << 4));
            }
#pragma unroll
            for (int mi = 0; mi < 4; ++mi)
#pragma unroll
                for (int ni = 0; ni < 4; ++ni)
                    acc[mi][ni] = __builtin_amdgcn_mfma_f32_16x16x32_bf16(
                        a[mi], b[ni], acc[mi][ni], 0, 0, 0);
        }
        __builtin_amdgcn_s_setprio(0);
    };
    auto boundary = [&](int n) {   // counted wait + barrier
        if (n == 8) asm volatile("s_waitcnt vmcnt(8)" ::: "memory");
        else        asm volatile("s_waitcnt vmcnt(0)" ::: "memory");
        asm volatile("s_waitcnt lgkmcnt(0)" ::: "memory");
        __builtin_amdgcn_s_barrier();
        __builtin_amdgcn_sched_barrier(0);
    };

    // ---- prologue: bias, qb0->vA, quant, As[0] half0, B(step0), qb1->vB --
    float bv[4];
#pragma unroll
    for (int ni = 0; ni < 4; ++ni)
        bv[ni] = bias[tN * 256 + wn * 64 + ni * 16 + lr];
    loadX(vA, 0);
    quantX(vA);                 // compiler waits X0
    writeA(0, 0);               // half0 of qb0 -> As[0] (step 0)
    stageB(0, 0);
    __builtin_amdgcn_sched_barrier(0);
    loadX(vB, 1);               // qb1 in flight
    // FIFO: [bias.4][B0.8][X_B.8] -> drain bias+B0, float X_B
    boundary(8);

    // ---- main: 8 steps; As/Bs double-buffered; quant at odd t -------------
    // t0: stage B1, load qb2->vA,  MFMA(buf0), writeA(As[1], qb0 half1)
    stageB(1, 1);
    __builtin_amdgcn_sched_barrier(0);
    loadX(vA, 2);
    writeA(1, 1);
    mfmaStep(0);
    boundary(8);     // [X_B.8][B1.8][X_A.8] -> drain X_B+B1, float X_A

    // t1: stage B2, quant qb1 (vB retired), MFMA(buf1), writeA(As[0], h0)
    stageB(0, 2);
    quantX(vB);
    writeA(0, 0);
    mfmaStep(1);
    boundary(0);     // [X_A.8][B2.8] -> drain both (X_A in flight 1.5 iters)

    // t2: stage B3, load qb3->vB, MFMA(buf0), writeA(As[1], qb1 half1)
    stageB(1, 3);
    __builtin_amdgcn_sched_barrier(0);
    loadX(vB, 3);
    writeA(1, 1);
    mfmaStep(0);
    boundary(8);     // [B3.8][X_B.8] -> drain B3, float X_B

    // t3: stage B4, quant qb2 (vA retired at t1), MFMA(buf1), writeA h0
    stageB(0, 4);
    quantX(vA);
    writeA(0, 0);
    mfmaStep(1);
    boundary(0);     // [X_B.8][B4.8] -> drain both (X_B 1.5 iters)

    // t4: stage B5, MFMA(buf0), writeA(As[1], qb2 half1)
    stageB(1, 5);
    writeA(1, 1);
    mfmaStep(0);
    boundary(0);

    // t5: stage B6, quant qb3 (vB retired at t3), MFMA(buf1), writeA h0
    stageB(0, 6);
    quantX(vB);
    writeA(0, 0);
    mfmaStep(1);
    boundary(0);

    // t6: stage B7, MFMA(buf0), writeA(As[1], qb3 half1)
    stageB(1, 7);
    writeA(1, 1);
    mfmaStep(0);
    boundary(0);

    // t7: MFMA(buf1), no boundary
    mfmaStep(1);

    // ---- epilogue: C/D layout col=lane&15, row=(lane>>4)*4+e --------------
#pragma unroll
    for (int ni = 0; ni < 4; ++ni) {
        int col = wn * 64 + ni * 16 + lr;
#pragma unroll
        for (int mi = 0; mi < 4; ++mi) {
            int r0 = mi * 16 + lg * 4;
#pragma unroll
            for (int e = 0; e < 4; ++e)
                Cb[(size_t)(r0 + e) * N + col] = acc[mi][ni][e] + bv[ni];
        }
    }
}

// ---------------------------------------------------------------------------
extern "C" void kernel_launch(void* const* d_in, const int* in_sizes, int n_in,
                              void* d_out, int out_size, void* d_ws, size_t ws_size,
                              hipStream_t stream) {
    const float* X    = (const float*)d_in[0];
    const float* W    = (const float*)d_in[1];
    const float* bias = (const float*)d_in[2];
    const int K = 512;
    const int M = in_sizes[0] / K;   // 65536

    __hip_bfloat16* Wt = (__hip_bfloat16*)d_ws;   // 512*512*2 = 512 KB

    wdq_kernel<<<dim3(512), dim3(128), 0, stream>>>(W, Wt);
    fused_gemm<<<dim3((M / 64) * (512 / 256)), dim3(256), 0, stream>>>(
        X, Wt, bias, (float*)d_out, M);
}